// Round 1
// baseline (1352.788 us; speedup 1.0000x reference)
//
#include <hip/hip_runtime.h>
#include <hip/hip_bf16.h>

// Problem dims (fixed by reference setup_inputs):
//   B=64, T=512, V=512, H=256, O=512
//   M1 = B*T = 32768 rows
// d_in order: sentence, prev_state, W_ih, b_ih, W_hh, b_hh, W_out, b_out
// d_out: tags [B,T,O] fp32 (16777216) then h_n [1,B,H] fp32 (16384)

typedef __attribute__((ext_vector_type(8))) short short8;
typedef __attribute__((ext_vector_type(4))) float floatx4;

__device__ __forceinline__ short f2b(float x) {
    unsigned u = __builtin_bit_cast(unsigned, x);
    unsigned r = (u + 0x7FFFu + ((u >> 16) & 1u)) >> 16;   // RNE
    return (short)r;
}

// ---------------- fp32 -> bf16 convert (vector4) ----------------
__global__ void conv_f32_bf16(const float* __restrict__ in, short* __restrict__ out, int n4) {
    int idx = blockIdx.x * blockDim.x + threadIdx.x;
    if (idx >= n4) return;
    float4 v = ((const float4*)in)[idx];
    short4 s;
    s.x = f2b(v.x); s.y = f2b(v.y); s.z = f2b(v.z); s.w = f2b(v.w);
    ((short4*)out)[idx] = s;
}

// ---------------- GEMM1: x_proj = sentence_bf16 [32768,512] @ W_ih^T + b_ih -> fp32 [32768,256]
// block = 256 threads (4 waves); wave w covers rows m0..m0+15, all 256 cols (16 n-tiles)
__global__ __launch_bounds__(256) void gemm1_xproj(const short* __restrict__ A,
                                                   const short* __restrict__ Bw,   // W_ih bf16 [256,512]
                                                   const float* __restrict__ bias, // b_ih [256]
                                                   float* __restrict__ C) {        // [32768,256]
    const int K = 512, N = 256;
    int wave = threadIdx.x >> 6;
    int lane = threadIdx.x & 63;
    int row  = lane & 15;
    int quad = lane >> 4;
    int m0 = blockIdx.x * 64 + wave * 16;

    floatx4 acc[16];
#pragma unroll
    for (int i = 0; i < 16; i++) acc[i] = (floatx4){0.f, 0.f, 0.f, 0.f};

    const short* pa = A + (size_t)(m0 + row) * K + quad * 8;
    for (int k0 = 0; k0 < K; k0 += 32) {
        short8 a = *(const short8*)(pa + k0);
#pragma unroll
        for (int nt = 0; nt < 16; nt++) {
            const short* pb = Bw + (size_t)(nt * 16 + row) * K + quad * 8 + k0;
            short8 b = *(const short8*)pb;
            acc[nt] = __builtin_amdgcn_mfma_f32_16x16x32_bf16(a, b, acc[nt], 0, 0, 0);
        }
    }
    // C/D layout: col = lane&15, row = quad*4 + r  [verified mapping]
#pragma unroll
    for (int nt = 0; nt < 16; nt++) {
        int n = nt * 16 + row;
        float bn = bias[n];
#pragma unroll
        for (int r = 0; r < 4; r++) {
            int m = m0 + quad * 4 + r;
            C[(size_t)m * N + n] = acc[nt][r] + bn;
        }
    }
}

// ---------------- Recurrence: h_t = relu(xp_t + h_{t-1} @ W_hh^T + b_hh)
// 64 blocks (one per batch row), 256 threads (one per hidden unit).
// Thread i holds W_hh[i][:] in 256 VGPRs; h broadcast from LDS.
__global__ __launch_bounds__(256, 1) void rnn_recur(const float* __restrict__ xp,    // [B,T,H]
                                                    const float* __restrict__ h0,    // [1,B,H]
                                                    const float* __restrict__ W_hh,  // [H,H]
                                                    const float* __restrict__ b_hh,  // [H]
                                                    short* __restrict__ hact,        // bf16 [B,T,H]
                                                    float* __restrict__ h_n) {       // [B,H]
    const int Hh = 256, T = 512;
    int b = blockIdx.x;
    int i = threadIdx.x;

    float4 wv[64];
    const float4* wr = (const float4*)(W_hh + (size_t)i * Hh);
#pragma unroll
    for (int j = 0; j < 64; j++) wv[j] = wr[j];

    __shared__ float sh[256];
    float h = h0[b * Hh + i];
    sh[i] = h;
    float bias = b_hh[i];
    const float* xpb = xp + (size_t)b * T * Hh;
    short* hb = hact + (size_t)b * T * Hh;
    __syncthreads();

    float xv = xpb[i];   // t = 0
    float hlast = h;
    for (int t = 0; t < T; t++) {
        // prefetch next step's x_proj early so the global load overlaps the dot
        float xn = (t + 1 < T) ? xpb[(size_t)(t + 1) * Hh + i] : 0.f;
        float a0 = 0.f, a1 = 0.f, a2 = 0.f, a3 = 0.f;
#pragma unroll
        for (int j = 0; j < 64; j++) {
            float4 hv = *(const float4*)(sh + j * 4);   // same addr all lanes -> broadcast
            a0 += hv.x * wv[j].x;
            a1 += hv.y * wv[j].y;
            a2 += hv.z * wv[j].z;
            a3 += hv.w * wv[j].w;
        }
        float acc = bias + xv + ((a0 + a1) + (a2 + a3));
        acc = fmaxf(acc, 0.f);
        __syncthreads();              // everyone done reading old h
        sh[i] = acc;
        hb[(size_t)t * Hh + i] = f2b(fminf(acc, 1.f));  // capped_lrelu(h>=0) = min(h,1)
        hlast = acc;
        xv = xn;
        __syncthreads();              // new h visible
    }
    h_n[b * Hh + i] = hlast;
}

// ---------------- GEMM3: tags = sigmoid(hidden_bf16 [32768,256] @ W_out^T + b_out) -> fp32 [32768,512]
// grid (M/64, 2): blockIdx.y selects 256-wide n-half.
__global__ __launch_bounds__(256) void gemm3_tags(const short* __restrict__ A,      // hidden bf16 [32768,256]
                                                  const short* __restrict__ Bw,     // W_out bf16 [512,256]
                                                  const float* __restrict__ bias,   // b_out [512]
                                                  float* __restrict__ C) {          // [32768,512]
    const int K = 256, N = 512;
    int wave = threadIdx.x >> 6;
    int lane = threadIdx.x & 63;
    int row  = lane & 15;
    int quad = lane >> 4;
    int m0 = blockIdx.x * 64 + wave * 16;
    int n_base = blockIdx.y * 256;

    floatx4 acc[16];
#pragma unroll
    for (int i = 0; i < 16; i++) acc[i] = (floatx4){0.f, 0.f, 0.f, 0.f};

    const short* pa = A + (size_t)(m0 + row) * K + quad * 8;
    for (int k0 = 0; k0 < K; k0 += 32) {
        short8 a = *(const short8*)(pa + k0);
#pragma unroll
        for (int nt = 0; nt < 16; nt++) {
            const short* pb = Bw + (size_t)(n_base + nt * 16 + row) * K + quad * 8 + k0;
            short8 b = *(const short8*)pb;
            acc[nt] = __builtin_amdgcn_mfma_f32_16x16x32_bf16(a, b, acc[nt], 0, 0, 0);
        }
    }
#pragma unroll
    for (int nt = 0; nt < 16; nt++) {
        int n = n_base + nt * 16 + row;
        float bn = bias[n];
#pragma unroll
        for (int r = 0; r < 4; r++) {
            int m = m0 + quad * 4 + r;
            float v = acc[nt][r] + bn;
            C[(size_t)m * N + n] = 1.f / (1.f + __expf(-v));
        }
    }
}

extern "C" void kernel_launch(void* const* d_in, const int* in_sizes, int n_in,
                              void* d_out, int out_size, void* d_ws, size_t ws_size,
                              hipStream_t stream) {
    const float* sentence   = (const float*)d_in[0];  // [64,512,512]
    const float* prev_state = (const float*)d_in[1];  // [1,64,256]
    const float* W_ih       = (const float*)d_in[2];  // [256,512]
    const float* b_ih       = (const float*)d_in[3];  // [256]
    const float* W_hh       = (const float*)d_in[4];  // [256,256]
    const float* b_hh       = (const float*)d_in[5];  // [256]
    const float* W_out      = (const float*)d_in[6];  // [512,256]
    const float* b_out      = (const float*)d_in[7];  // [512]

    const size_t SENT_N  = 64u * 512u * 512u;   // 16777216
    const size_t WIH_N   = 256u * 512u;         // 131072
    const size_t WOUT_N  = 512u * 256u;         // 131072
    const size_t XPROJ_N = 32768u * 256u;       // 8388608
    const size_t HID_N   = 64u * 512u * 256u;   // 8388608

    char* w = (char*)d_ws;
    short* sent_bf = (short*)w;  w += SENT_N * sizeof(short);    // 33.5 MB
    short* wih_bf  = (short*)w;  w += WIH_N * sizeof(short);     // 256 KB
    short* wout_bf = (short*)w;  w += WOUT_N * sizeof(short);    // 256 KB
    float* xproj   = (float*)w;  w += XPROJ_N * sizeof(float);   // 33.5 MB
    short* hid_bf  = (short*)w;  w += HID_N * sizeof(short);     // 16.8 MB

    float* tags = (float*)d_out;                 // [32768,512]
    float* h_n  = (float*)d_out + 16777216;      // [64,256]

    // 1. converts
    conv_f32_bf16<<<(int)(SENT_N / 4 / 256), 256, 0, stream>>>(sentence, sent_bf, (int)(SENT_N / 4));
    conv_f32_bf16<<<(int)(WIH_N / 4 / 256),  256, 0, stream>>>(W_ih,  wih_bf,  (int)(WIH_N / 4));
    conv_f32_bf16<<<(int)(WOUT_N / 4 / 256), 256, 0, stream>>>(W_out, wout_bf, (int)(WOUT_N / 4));

    // 2. x_proj GEMM (bf16 MFMA, fp32 out)
    gemm1_xproj<<<512, 256, 0, stream>>>(sent_bf, wih_bf, b_ih, xproj);

    // 3. sequential recurrence (fp32), writes capped hidden as bf16 + h_n
    rnn_recur<<<64, 256, 0, stream>>>(xproj, prev_state, W_hh, b_hh, hid_bf, h_n);

    // 4. output GEMM + sigmoid
    gemm3_tags<<<dim3(512, 2), 256, 0, stream>>>(hid_bf, wout_bf, b_out, tags);
}

// Round 2
// 826.311 us; speedup vs baseline: 1.6371x; 1.6371x over previous
//
#include <hip/hip_runtime.h>
#include <hip/hip_bf16.h>

// Dims: B=64, T=512, V=512, H=256, O=512. M1 = B*T = 32768.
// d_in: sentence, prev_state, W_ih, b_ih, W_hh, b_hh, W_out, b_out
// d_out: tags [B,T,O] fp32 (16777216) then h_n [1,B,H] fp32 (16384)

typedef __attribute__((ext_vector_type(8))) _Float16 half8;
typedef __attribute__((ext_vector_type(4))) _Float16 half4;
typedef __attribute__((ext_vector_type(4))) float   floatx4;

// ---------------- fp32 -> fp16 convert (vector4) ----------------
__global__ void conv_f32_f16(const float* __restrict__ in, _Float16* __restrict__ out, int n4) {
    int idx = blockIdx.x * blockDim.x + threadIdx.x;
    if (idx >= n4) return;
    float4 v = ((const float4*)in)[idx];
    half4 h = { (_Float16)v.x, (_Float16)v.y, (_Float16)v.z, (_Float16)v.w };
    ((half4*)out)[idx] = h;
}

// ---------------- GEMM1: xp = sentence [32768,512] @ W_ih^T + (b_ih + b_hh) -> fp32 [B,T,H]
// sentence read fp32, converted to fp16 inline. b_hh folded in so rnn skips it.
__global__ __launch_bounds__(256) void gemm1_xproj(const float* __restrict__ A,      // sentence fp32
                                                   const _Float16* __restrict__ Bw,  // W_ih f16 [256,512]
                                                   const float* __restrict__ b_ih,
                                                   const float* __restrict__ b_hh,
                                                   float* __restrict__ C) {          // [32768,256]
    const int K = 512, N = 256;
    int wave = threadIdx.x >> 6;
    int lane = threadIdx.x & 63;
    int row  = lane & 15;
    int quad = lane >> 4;
    int m0 = blockIdx.x * 64 + wave * 16;

    floatx4 acc[16];
#pragma unroll
    for (int i = 0; i < 16; i++) acc[i] = (floatx4){0.f, 0.f, 0.f, 0.f};

    const float* pa = A + (size_t)(m0 + row) * K + quad * 8;
    for (int k0 = 0; k0 < K; k0 += 32) {
        float4 a0 = *(const float4*)(pa + k0);
        float4 a1 = *(const float4*)(pa + k0 + 4);
        half8 a = { (_Float16)a0.x, (_Float16)a0.y, (_Float16)a0.z, (_Float16)a0.w,
                    (_Float16)a1.x, (_Float16)a1.y, (_Float16)a1.z, (_Float16)a1.w };
#pragma unroll
        for (int nt = 0; nt < 16; nt++) {
            const _Float16* pb = Bw + (size_t)(nt * 16 + row) * K + quad * 8 + k0;
            half8 b = *(const half8*)pb;
            acc[nt] = __builtin_amdgcn_mfma_f32_16x16x32_f16(a, b, acc[nt], 0, 0, 0);
        }
    }
    // D layout: col = lane&15 (= n here), row = quad*4 + r (= m)
#pragma unroll
    for (int nt = 0; nt < 16; nt++) {
        int n = nt * 16 + row;
        float bn = b_ih[n] + b_hh[n];
#pragma unroll
        for (int r = 0; r < 4; r++) {
            int m = m0 + quad * 4 + r;
            C[(size_t)m * N + n] = acc[nt][r] + bn;
        }
    }
}

// ---------------- Recurrence (MFMA): 4 blocks x 16 batch rows, 256 threads (4 waves, 1/SIMD).
// Per step: g^T[n][m] = sum_k W_hh[n][k] * h[m][k] via mfma_f32_16x16x32_f16.
//   A-operand = W_hh frags (static, 128 VGPRs). B-operand = h frags from LDS (double-buffered).
// D layout (col=lane&15=m, row=quad*4+r=n-within-tile) writes straight back as packed half4:
//   LDS h-buffer [16][264] f16 (pad 8 -> banks (4c+4q)%32, conflict-free), global hid, h_n.
__global__ __launch_bounds__(256, 1) void rnn_recur(const float* __restrict__ xp,    // [B,T,H] fp32 (bias incl.)
                                                    const float* __restrict__ h0,    // [1,B,H] fp32
                                                    const float* __restrict__ W_hh,  // [H,H] fp32
                                                    _Float16* __restrict__ hid,      // f16 [B,T,H] capped
                                                    float* __restrict__ h_n) {       // [B,H] fp32
    const int Hh = 256, T = 512, LD = 264;   // LDS row stride in halves (528 B)
    int b0   = blockIdx.x * 16;
    int wave = threadIdx.x >> 6;
    int lane = threadIdx.x & 63;
    int c    = lane & 15;       // batch col within tile
    int q    = lane >> 4;

    // --- W_hh fragments into registers: wf[nt][kt], n = (wave*4+nt)*16 + c, k = kt*32 + q*8
    half8 wf[4][8];
#pragma unroll
    for (int nt = 0; nt < 4; nt++) {
        int n = (wave * 4 + nt) * 16 + c;
        const float* wr = W_hh + (size_t)n * Hh + q * 8;
#pragma unroll
        for (int kt = 0; kt < 8; kt++) {
            float4 x0 = *(const float4*)(wr + kt * 32);
            float4 x1 = *(const float4*)(wr + kt * 32 + 4);
            wf[nt][kt] = (half8){ (_Float16)x0.x, (_Float16)x0.y, (_Float16)x0.z, (_Float16)x0.w,
                                  (_Float16)x1.x, (_Float16)x1.y, (_Float16)x1.z, (_Float16)x1.w };
        }
    }

    __shared__ _Float16 hb[2][16][LD];
    // h0 -> buffer 0
    for (int idx = threadIdx.x; idx < 16 * 256; idx += 256) {
        int m = idx >> 8, k = idx & 255;
        hb[0][m][k] = (_Float16)h0[(size_t)(b0 + m) * Hh + k];
    }
    __syncthreads();

    // xp base for this lane: batch row b0+c, n-chunk (wave*4+nt)*16 + q*4 (+r)
    const float* xpb = xp + (size_t)(b0 + c) * T * Hh;
    _Float16* hidb = hid + (size_t)(b0 + c) * T * Hh;

    float4 xq[4];
#pragma unroll
    for (int nt = 0; nt < 4; nt++)
        xq[nt] = *(const float4*)(xpb + (size_t)0 * Hh + (wave * 4 + nt) * 16 + q * 4);

    for (int t = 0; t < T; t++) {
        // prefetch next step's x_proj (independent of the recurrence chain)
        int tn = (t < T - 1) ? t + 1 : T - 1;
        float4 xn[4];
#pragma unroll
        for (int nt = 0; nt < 4; nt++)
            xn[nt] = *(const float4*)(xpb + (size_t)tn * Hh + (wave * 4 + nt) * 16 + q * 4);

        const _Float16* hr = &hb[t & 1][0][0];
        floatx4 acc[4];
#pragma unroll
        for (int nt = 0; nt < 4; nt++) acc[nt] = (floatx4){0.f, 0.f, 0.f, 0.f};
#pragma unroll
        for (int kt = 0; kt < 8; kt++) {
            half8 hf = *(const half8*)(hr + c * LD + kt * 32 + q * 8);   // B frag: m=c, k=kt*32+q*8
#pragma unroll
            for (int nt = 0; nt < 4; nt++)
                acc[nt] = __builtin_amdgcn_mfma_f32_16x16x32_f16(wf[nt][kt], hf, acc[nt], 0, 0, 0);
        }

        _Float16* hw = &hb[(t + 1) & 1][0][0];
#pragma unroll
        for (int nt = 0; nt < 4; nt++) {
            int n0 = (wave * 4 + nt) * 16 + q * 4;
            float v0 = fmaxf(acc[nt][0] + xq[nt].x, 0.f);
            float v1 = fmaxf(acc[nt][1] + xq[nt].y, 0.f);
            float v2 = fmaxf(acc[nt][2] + xq[nt].z, 0.f);
            float v3 = fmaxf(acc[nt][3] + xq[nt].w, 0.f);
            half4 hv = { (_Float16)v0, (_Float16)v1, (_Float16)v2, (_Float16)v3 };
            *(half4*)(hw + c * LD + n0) = hv;                             // next step's B source
            half4 hc = { (_Float16)fminf(v0, 1.f), (_Float16)fminf(v1, 1.f),
                         (_Float16)fminf(v2, 1.f), (_Float16)fminf(v3, 1.f) };
            *(half4*)(hidb + (size_t)t * Hh + n0) = hc;                   // capped hidden for GEMM3
            if (t == T - 1) {
                float4 hn = { v0, v1, v2, v3 };
                *(float4*)(h_n + (size_t)(b0 + c) * Hh + n0) = hn;
            }
            xq[nt] = xn[nt];
        }
        __syncthreads();
    }
}

// ---------------- GEMM3: tags = sigmoid(hid f16 [32768,256] @ W_out^T + b_out) -> fp32 [32768,512]
__global__ __launch_bounds__(256) void gemm3_tags(const _Float16* __restrict__ A,
                                                  const _Float16* __restrict__ Bw,   // W_out f16 [512,256]
                                                  const float* __restrict__ bias,
                                                  float* __restrict__ C) {
    const int K = 256, N = 512;
    int wave = threadIdx.x >> 6;
    int lane = threadIdx.x & 63;
    int row  = lane & 15;
    int quad = lane >> 4;
    int m0 = blockIdx.x * 64 + wave * 16;
    int n_base = blockIdx.y * 256;

    floatx4 acc[16];
#pragma unroll
    for (int i = 0; i < 16; i++) acc[i] = (floatx4){0.f, 0.f, 0.f, 0.f};

    const _Float16* pa = A + (size_t)(m0 + row) * K + quad * 8;
    for (int k0 = 0; k0 < K; k0 += 32) {
        half8 a = *(const half8*)(pa + k0);
#pragma unroll
        for (int nt = 0; nt < 16; nt++) {
            const _Float16* pb = Bw + (size_t)(n_base + nt * 16 + row) * K + quad * 8 + k0;
            half8 b = *(const half8*)pb;
            acc[nt] = __builtin_amdgcn_mfma_f32_16x16x32_f16(a, b, acc[nt], 0, 0, 0);
        }
    }
#pragma unroll
    for (int nt = 0; nt < 16; nt++) {
        int n = n_base + nt * 16 + row;
        float bn = bias[n];
#pragma unroll
        for (int r = 0; r < 4; r++) {
            int m = m0 + quad * 4 + r;
            float v = acc[nt][r] + bn;
            C[(size_t)m * N + n] = 1.f / (1.f + __expf(-v));
        }
    }
}

extern "C" void kernel_launch(void* const* d_in, const int* in_sizes, int n_in,
                              void* d_out, int out_size, void* d_ws, size_t ws_size,
                              hipStream_t stream) {
    const float* sentence   = (const float*)d_in[0];  // [64,512,512]
    const float* prev_state = (const float*)d_in[1];  // [1,64,256]
    const float* W_ih       = (const float*)d_in[2];  // [256,512]
    const float* b_ih       = (const float*)d_in[3];  // [256]
    const float* W_hh       = (const float*)d_in[4];  // [256,256]
    const float* b_hh       = (const float*)d_in[5];  // [256]
    const float* W_out      = (const float*)d_in[6];  // [512,256]
    const float* b_out      = (const float*)d_in[7];  // [512]

    const size_t WIH_N   = 256u * 512u;
    const size_t WOUT_N  = 512u * 256u;
    const size_t XPROJ_N = 32768u * 256u;
    const size_t HID_N   = 64u * 512u * 256u;

    char* w = (char*)d_ws;
    _Float16* wih_f  = (_Float16*)w;  w += WIH_N * sizeof(_Float16);    // 256 KB
    _Float16* wout_f = (_Float16*)w;  w += WOUT_N * sizeof(_Float16);   // 256 KB
    float*    xproj  = (float*)w;     w += XPROJ_N * sizeof(float);     // 33.5 MB
    _Float16* hid_f  = (_Float16*)w;  w += HID_N * sizeof(_Float16);    // 16.8 MB

    float* tags = (float*)d_out;
    float* h_n  = (float*)d_out + 16777216;

    conv_f32_f16<<<(int)(WIH_N / 4 / 256),  256, 0, stream>>>(W_ih,  wih_f,  (int)(WIH_N / 4));
    conv_f32_f16<<<(int)(WOUT_N / 4 / 256), 256, 0, stream>>>(W_out, wout_f, (int)(WOUT_N / 4));

    gemm1_xproj<<<512, 256, 0, stream>>>(sentence, wih_f, b_ih, b_hh, xproj);

    rnn_recur<<<4, 256, 0, stream>>>(xproj, prev_state, W_hh, hid_f, h_n);

    gemm3_tags<<<dim3(512, 2), 256, 0, stream>>>(hid_f, wout_f, b_out, tags);
}

// Round 3
// 821.450 us; speedup vs baseline: 1.6468x; 1.0059x over previous
//
#include <hip/hip_runtime.h>
#include <hip/hip_bf16.h>

// Dims: B=64, T=512, V=512, H=256, O=512. M1 = B*T = 32768.
// d_in: sentence, prev_state, W_ih, b_ih, W_hh, b_hh, W_out, b_out
// d_out: tags [B,T,O] fp32 (16777216) then h_n [1,B,H] fp32 (16384)

typedef __attribute__((ext_vector_type(8))) _Float16 half8;
typedef __attribute__((ext_vector_type(4))) _Float16 half4;
typedef __attribute__((ext_vector_type(4))) float   floatx4;

// LDS-only barrier: waits LDS ops, does NOT drain vmcnt — global loads/stores
// stay in flight across the barrier (this was the 2670-cyc/step stall: plain
// __syncthreads() emits s_waitcnt vmcnt(0) and serialized an HBM round-trip
// into every recurrence step).
__device__ __forceinline__ void lds_barrier() {
    asm volatile("s_waitcnt lgkmcnt(0)\n\ts_barrier" ::: "memory");
}

// ---------------- fp32 -> fp16 convert (vector4) ----------------
__global__ void conv_f32_f16(const float* __restrict__ in, _Float16* __restrict__ out, int n4) {
    int idx = blockIdx.x * blockDim.x + threadIdx.x;
    if (idx >= n4) return;
    float4 v = ((const float4*)in)[idx];
    half4 h = { (_Float16)v.x, (_Float16)v.y, (_Float16)v.z, (_Float16)v.w };
    ((half4*)out)[idx] = h;
}

// ---------------- GEMM1: xp = sentence [32768,512] @ W_ih^T + (b_ih + b_hh) -> fp32 [B,T,H]
__global__ __launch_bounds__(256) void gemm1_xproj(const float* __restrict__ A,      // sentence fp32
                                                   const _Float16* __restrict__ Bw,  // W_ih f16 [256,512]
                                                   const float* __restrict__ b_ih,
                                                   const float* __restrict__ b_hh,
                                                   float* __restrict__ C) {          // [32768,256]
    const int K = 512, N = 256;
    int wave = threadIdx.x >> 6;
    int lane = threadIdx.x & 63;
    int row  = lane & 15;
    int quad = lane >> 4;
    int m0 = blockIdx.x * 64 + wave * 16;

    floatx4 acc[16];
#pragma unroll
    for (int i = 0; i < 16; i++) acc[i] = (floatx4){0.f, 0.f, 0.f, 0.f};

    const float* pa = A + (size_t)(m0 + row) * K + quad * 8;
    for (int k0 = 0; k0 < K; k0 += 32) {
        float4 a0 = *(const float4*)(pa + k0);
        float4 a1 = *(const float4*)(pa + k0 + 4);
        half8 a = { (_Float16)a0.x, (_Float16)a0.y, (_Float16)a0.z, (_Float16)a0.w,
                    (_Float16)a1.x, (_Float16)a1.y, (_Float16)a1.z, (_Float16)a1.w };
#pragma unroll
        for (int nt = 0; nt < 16; nt++) {
            const _Float16* pb = Bw + (size_t)(nt * 16 + row) * K + quad * 8 + k0;
            half8 b = *(const half8*)pb;
            acc[nt] = __builtin_amdgcn_mfma_f32_16x16x32_f16(a, b, acc[nt], 0, 0, 0);
        }
    }
#pragma unroll
    for (int nt = 0; nt < 16; nt++) {
        int n = nt * 16 + row;
        float bn = b_ih[n] + b_hh[n];
#pragma unroll
        for (int r = 0; r < 4; r++) {
            int m = m0 + quad * 4 + r;
            C[(size_t)m * N + n] = acc[nt][r] + bn;
        }
    }
}

// ---------------- Recurrence (MFMA): 4 blocks x 16 batch rows, 256 threads (4 waves, 1/SIMD).
// A-operand = W_hh frags (static in regs). B-operand = h frags from LDS (ping-pong).
// Barrier is LDS-only; xp prefetch is 2 steps deep so HBM latency stays hidden.
__global__ __launch_bounds__(256, 1) void rnn_recur(const float* __restrict__ xp,    // [B,T,H] fp32 (bias incl.)
                                                    const float* __restrict__ h0,    // [1,B,H] fp32
                                                    const float* __restrict__ W_hh,  // [H,H] fp32
                                                    _Float16* __restrict__ hid,      // f16 [B,T,H] capped
                                                    float* __restrict__ h_n) {       // [B,H] fp32
    const int Hh = 256, T = 512, LD = 264;   // LDS row stride in halves
    int b0   = blockIdx.x * 16;
    int wave = threadIdx.x >> 6;
    int lane = threadIdx.x & 63;
    int c    = lane & 15;       // batch col within tile
    int q    = lane >> 4;

    // W_hh fragments: wf[nt][kt], n = (wave*4+nt)*16 + c, k = kt*32 + q*8
    half8 wf[4][8];
#pragma unroll
    for (int nt = 0; nt < 4; nt++) {
        int n = (wave * 4 + nt) * 16 + c;
        const float* wr = W_hh + (size_t)n * Hh + q * 8;
#pragma unroll
        for (int kt = 0; kt < 8; kt++) {
            float4 x0 = *(const float4*)(wr + kt * 32);
            float4 x1 = *(const float4*)(wr + kt * 32 + 4);
            wf[nt][kt] = (half8){ (_Float16)x0.x, (_Float16)x0.y, (_Float16)x0.z, (_Float16)x0.w,
                                  (_Float16)x1.x, (_Float16)x1.y, (_Float16)x1.z, (_Float16)x1.w };
        }
    }

    __shared__ _Float16 hb[2][16][LD];
    for (int idx = threadIdx.x; idx < 16 * 256; idx += 256) {
        int m = idx >> 8, k = idx & 255;
        hb[0][m][k] = (_Float16)h0[(size_t)(b0 + m) * Hh + k];
    }
    __syncthreads();   // once, before the loop — full drain is fine here

    const float* xpb = xp + (size_t)(b0 + c) * T * Hh;
    _Float16* hidb = hid + (size_t)(b0 + c) * T * Hh;

    // 2-deep xp prefetch pipeline: xA = step t, xB = step t+1
    float4 xA[4], xB[4];
#pragma unroll
    for (int nt = 0; nt < 4; nt++) {
        int off = (wave * 4 + nt) * 16 + q * 4;
        xA[nt] = *(const float4*)(xpb + (size_t)0 * Hh + off);
        xB[nt] = *(const float4*)(xpb + (size_t)1 * Hh + off);
    }

    for (int t = 0; t < T; t++) {
        // issue prefetch for step t+2 (not needed for ~2.5 steps)
        int tn = (t + 2 < T) ? t + 2 : T - 1;
        float4 xC[4];
#pragma unroll
        for (int nt = 0; nt < 4; nt++)
            xC[nt] = *(const float4*)(xpb + (size_t)tn * Hh + (wave * 4 + nt) * 16 + q * 4);

        const _Float16* hr = &hb[t & 1][0][0];
        floatx4 acc[4];
#pragma unroll
        for (int nt = 0; nt < 4; nt++) acc[nt] = (floatx4){0.f, 0.f, 0.f, 0.f};
#pragma unroll
        for (int kt = 0; kt < 8; kt++) {
            half8 hf = *(const half8*)(hr + c * LD + kt * 32 + q * 8);   // B frag: m=c, k=kt*32+q*8
#pragma unroll
            for (int nt = 0; nt < 4; nt++)
                acc[nt] = __builtin_amdgcn_mfma_f32_16x16x32_f16(wf[nt][kt], hf, acc[nt], 0, 0, 0);
        }

        _Float16* hw = &hb[(t + 1) & 1][0][0];
#pragma unroll
        for (int nt = 0; nt < 4; nt++) {
            int n0 = (wave * 4 + nt) * 16 + q * 4;
            float v0 = fmaxf(acc[nt][0] + xA[nt].x, 0.f);
            float v1 = fmaxf(acc[nt][1] + xA[nt].y, 0.f);
            float v2 = fmaxf(acc[nt][2] + xA[nt].z, 0.f);
            float v3 = fmaxf(acc[nt][3] + xA[nt].w, 0.f);
            half4 hv = { (_Float16)v0, (_Float16)v1, (_Float16)v2, (_Float16)v3 };
            *(half4*)(hw + c * LD + n0) = hv;                             // next step's B source
            half4 hc = { (_Float16)fminf(v0, 1.f), (_Float16)fminf(v1, 1.f),
                         (_Float16)fminf(v2, 1.f), (_Float16)fminf(v3, 1.f) };
            *(half4*)(hidb + (size_t)t * Hh + n0) = hc;                   // capped hidden for GEMM3
            if (t == T - 1) {
                float4 hn = { v0, v1, v2, v3 };
                *(float4*)(h_n + (size_t)(b0 + c) * Hh + n0) = hn;
            }
            xA[nt] = xB[nt];
            xB[nt] = xC[nt];
        }
        lds_barrier();   // LDS-only: global loads/stores remain in flight
    }
}

// ---------------- GEMM3: tags = sigmoid(hid f16 [32768,256] @ W_out^T + b_out) -> fp32 [32768,512]
__global__ __launch_bounds__(256) void gemm3_tags(const _Float16* __restrict__ A,
                                                  const _Float16* __restrict__ Bw,   // W_out f16 [512,256]
                                                  const float* __restrict__ bias,
                                                  float* __restrict__ C) {
    const int K = 256, N = 512;
    int wave = threadIdx.x >> 6;
    int lane = threadIdx.x & 63;
    int row  = lane & 15;
    int quad = lane >> 4;
    int m0 = blockIdx.x * 64 + wave * 16;
    int n_base = blockIdx.y * 256;

    floatx4 acc[16];
#pragma unroll
    for (int i = 0; i < 16; i++) acc[i] = (floatx4){0.f, 0.f, 0.f, 0.f};

    const _Float16* pa = A + (size_t)(m0 + row) * K + quad * 8;
    for (int k0 = 0; k0 < K; k0 += 32) {
        half8 a = *(const half8*)(pa + k0);
#pragma unroll
        for (int nt = 0; nt < 16; nt++) {
            const _Float16* pb = Bw + (size_t)(n_base + nt * 16 + row) * K + quad * 8 + k0;
            half8 b = *(const half8*)pb;
            acc[nt] = __builtin_amdgcn_mfma_f32_16x16x32_f16(a, b, acc[nt], 0, 0, 0);
        }
    }
#pragma unroll
    for (int nt = 0; nt < 16; nt++) {
        int n = n_base + nt * 16 + row;
        float bn = bias[n];
#pragma unroll
        for (int r = 0; r < 4; r++) {
            int m = m0 + quad * 4 + r;
            float v = acc[nt][r] + bn;
            C[(size_t)m * N + n] = 1.f / (1.f + __expf(-v));
        }
    }
}

extern "C" void kernel_launch(void* const* d_in, const int* in_sizes, int n_in,
                              void* d_out, int out_size, void* d_ws, size_t ws_size,
                              hipStream_t stream) {
    const float* sentence   = (const float*)d_in[0];  // [64,512,512]
    const float* prev_state = (const float*)d_in[1];  // [1,64,256]
    const float* W_ih       = (const float*)d_in[2];  // [256,512]
    const float* b_ih       = (const float*)d_in[3];  // [256]
    const float* W_hh       = (const float*)d_in[4];  // [256,256]
    const float* b_hh       = (const float*)d_in[5];  // [256]
    const float* W_out      = (const float*)d_in[6];  // [512,256]
    const float* b_out      = (const float*)d_in[7];  // [512]

    const size_t WIH_N   = 256u * 512u;
    const size_t WOUT_N  = 512u * 256u;
    const size_t XPROJ_N = 32768u * 256u;
    const size_t HID_N   = 64u * 512u * 256u;

    char* w = (char*)d_ws;
    _Float16* wih_f  = (_Float16*)w;  w += WIH_N * sizeof(_Float16);
    _Float16* wout_f = (_Float16*)w;  w += WOUT_N * sizeof(_Float16);
    float*    xproj  = (float*)w;     w += XPROJ_N * sizeof(float);
    _Float16* hid_f  = (_Float16*)w;  w += HID_N * sizeof(_Float16);

    float* tags = (float*)d_out;
    float* h_n  = (float*)d_out + 16777216;

    conv_f32_f16<<<(int)(WIH_N / 4 / 256),  256, 0, stream>>>(W_ih,  wih_f,  (int)(WIH_N / 4));
    conv_f32_f16<<<(int)(WOUT_N / 4 / 256), 256, 0, stream>>>(W_out, wout_f, (int)(WOUT_N / 4));

    gemm1_xproj<<<512, 256, 0, stream>>>(sentence, wih_f, b_ih, b_hh, xproj);

    rnn_recur<<<4, 256, 0, stream>>>(xproj, prev_state, W_hh, hid_f, h_n);

    gemm3_tags<<<dim3(512, 2), 256, 0, stream>>>(hid_f, wout_f, b_out, tags);
}

// Round 4
// 678.209 us; speedup vs baseline: 1.9946x; 1.2112x over previous
//
#include <hip/hip_runtime.h>
#include <hip/hip_bf16.h>

// Dims: B=64, T=512, V=512, H=256, O=512. M1 = B*T = 32768.
// d_in: sentence, prev_state, W_ih, b_ih, W_hh, b_hh, W_out, b_out
// d_out: tags [B,T,O] fp32 (16777216) then h_n [1,B,H] fp32 (16384)

typedef __attribute__((ext_vector_type(8))) _Float16 half8;
typedef __attribute__((ext_vector_type(4))) _Float16 half4;
typedef __attribute__((ext_vector_type(4))) float   floatx4;

// LDS-only barrier: waits LDS ops, does NOT drain vmcnt — global loads/stores
// stay in flight across it.
__device__ __forceinline__ void lds_barrier() {
    asm volatile("s_waitcnt lgkmcnt(0)\n\ts_barrier" ::: "memory");
}

// ---------------- fp32 -> fp16 convert (vector4) ----------------
__global__ void conv_f32_f16(const float* __restrict__ in, _Float16* __restrict__ out, int n4) {
    int idx = blockIdx.x * blockDim.x + threadIdx.x;
    if (idx >= n4) return;
    float4 v = ((const float4*)in)[idx];
    half4 h = { (_Float16)v.x, (_Float16)v.y, (_Float16)v.z, (_Float16)v.w };
    ((half4*)out)[idx] = h;
}

// ---------------- GEMM1: xp = sentence [32768,512] @ W_ih^T + (b_ih + b_hh) -> fp32 [B,T,H]
__global__ __launch_bounds__(256) void gemm1_xproj(const float* __restrict__ A,      // sentence fp32
                                                   const _Float16* __restrict__ Bw,  // W_ih f16 [256,512]
                                                   const float* __restrict__ b_ih,
                                                   const float* __restrict__ b_hh,
                                                   float* __restrict__ C) {          // [32768,256]
    const int K = 512, N = 256;
    int wave = threadIdx.x >> 6;
    int lane = threadIdx.x & 63;
    int row  = lane & 15;
    int quad = lane >> 4;
    int m0 = blockIdx.x * 64 + wave * 16;

    floatx4 acc[16];
#pragma unroll
    for (int i = 0; i < 16; i++) acc[i] = (floatx4){0.f, 0.f, 0.f, 0.f};

    const float* pa = A + (size_t)(m0 + row) * K + quad * 8;
    for (int k0 = 0; k0 < K; k0 += 32) {
        float4 a0 = *(const float4*)(pa + k0);
        float4 a1 = *(const float4*)(pa + k0 + 4);
        half8 a = { (_Float16)a0.x, (_Float16)a0.y, (_Float16)a0.z, (_Float16)a0.w,
                    (_Float16)a1.x, (_Float16)a1.y, (_Float16)a1.z, (_Float16)a1.w };
#pragma unroll
        for (int nt = 0; nt < 16; nt++) {
            const _Float16* pb = Bw + (size_t)(nt * 16 + row) * K + quad * 8 + k0;
            half8 b = *(const half8*)pb;
            acc[nt] = __builtin_amdgcn_mfma_f32_16x16x32_f16(a, b, acc[nt], 0, 0, 0);
        }
    }
#pragma unroll
    for (int nt = 0; nt < 16; nt++) {
        int n = nt * 16 + row;
        float bn = b_ih[n] + b_hh[n];
#pragma unroll
        for (int r = 0; r < 4; r++) {
            int m = m0 + quad * 4 + r;
            C[(size_t)m * N + n] = acc[nt][r] + bn;
        }
    }
}

// ---------------- Recurrence (MFMA): 4 blocks x 16 batch rows, 256 threads (4 waves, 1/SIMD).
// A-operand = W_hh frags (static in regs/AGPRs). B-operand = h frags from LDS (ping-pong).
// xp prefetch: consume-then-reload, loop unrolled x2, so each load has ~2 full
// step-bodies in flight before its waitcnt (round-3 bug: register rotation movs
// forced the vmcnt wait into the SAME step that issued the load).
__global__ __launch_bounds__(256, 1) void rnn_recur(const float* __restrict__ xp,    // [B,T,H] fp32 (bias incl.)
                                                    const float* __restrict__ h0,    // [1,B,H] fp32
                                                    const float* __restrict__ W_hh,  // [H,H] fp32
                                                    _Float16* __restrict__ hid,      // f16 [B,T,H] capped
                                                    float* __restrict__ h_n) {       // [B,H] fp32
    const int Hh = 256, T = 512, LD = 264;   // LDS row stride in halves
    int b0   = blockIdx.x * 16;
    int wave = threadIdx.x >> 6;
    int lane = threadIdx.x & 63;
    int c    = lane & 15;       // batch col within tile
    int q    = lane >> 4;

    // W_hh fragments: wf[nt][kt], n = (wave*4+nt)*16 + c, k = kt*32 + q*8
    half8 wf[4][8];
#pragma unroll
    for (int nt = 0; nt < 4; nt++) {
        int n = (wave * 4 + nt) * 16 + c;
        const float* wr = W_hh + (size_t)n * Hh + q * 8;
#pragma unroll
        for (int kt = 0; kt < 8; kt++) {
            float4 x0 = *(const float4*)(wr + kt * 32);
            float4 x1 = *(const float4*)(wr + kt * 32 + 4);
            wf[nt][kt] = (half8){ (_Float16)x0.x, (_Float16)x0.y, (_Float16)x0.z, (_Float16)x0.w,
                                  (_Float16)x1.x, (_Float16)x1.y, (_Float16)x1.z, (_Float16)x1.w };
        }
    }

    __shared__ _Float16 hb[2][16][LD];
    for (int idx = threadIdx.x; idx < 16 * 256; idx += 256) {
        int m = idx >> 8, k = idx & 255;
        hb[0][m][k] = (_Float16)h0[(size_t)(b0 + m) * Hh + k];
    }
    __syncthreads();   // once, before the loop

    const float* xpb = xp + (size_t)(b0 + c) * T * Hh;
    _Float16* hidb = hid + (size_t)(b0 + c) * T * Hh;

    // per-nt n-offset for this lane's xp/hid/h_n accesses
    int noff[4];
#pragma unroll
    for (int nt = 0; nt < 4; nt++) noff[nt] = (wave * 4 + nt) * 16 + q * 4;

    // two prefetch slots: slot0 = even steps, slot1 = odd steps
    float4 xq0[4], xq1[4];
#pragma unroll
    for (int nt = 0; nt < 4; nt++) {
        xq0[nt] = *(const float4*)(xpb + (size_t)0 * Hh + noff[nt]);
        xq1[nt] = *(const float4*)(xpb + (size_t)1 * Hh + noff[nt]);
    }

    auto do_step = [&](int t, float4 (&xq)[4]) {
        const _Float16* hr = &hb[t & 1][0][0];
        floatx4 acc[4];
#pragma unroll
        for (int nt = 0; nt < 4; nt++) acc[nt] = (floatx4){0.f, 0.f, 0.f, 0.f};
#pragma unroll
        for (int kt = 0; kt < 8; kt++) {
            half8 hf = *(const half8*)(hr + c * LD + kt * 32 + q * 8);   // B frag: m=c, k=kt*32+q*8
#pragma unroll
            for (int nt = 0; nt < 4; nt++)
                acc[nt] = __builtin_amdgcn_mfma_f32_16x16x32_f16(wf[nt][kt], hf, acc[nt], 0, 0, 0);
        }

        _Float16* hw = &hb[(t + 1) & 1][0][0];
#pragma unroll
        for (int nt = 0; nt < 4; nt++) {
            float v0 = fmaxf(acc[nt][0] + xq[nt].x, 0.f);
            float v1 = fmaxf(acc[nt][1] + xq[nt].y, 0.f);
            float v2 = fmaxf(acc[nt][2] + xq[nt].z, 0.f);
            float v3 = fmaxf(acc[nt][3] + xq[nt].w, 0.f);
            half4 hv = { (_Float16)v0, (_Float16)v1, (_Float16)v2, (_Float16)v3 };
            *(half4*)(hw + c * LD + noff[nt]) = hv;                       // next step's B source
            half4 hc = { (_Float16)fminf(v0, 1.f), (_Float16)fminf(v1, 1.f),
                         (_Float16)fminf(v2, 1.f), (_Float16)fminf(v3, 1.f) };
            *(half4*)(hidb + (size_t)t * Hh + noff[nt]) = hc;             // capped hidden for GEMM3
            if (t == T - 1) {
                float4 hn = { v0, v1, v2, v3 };
                *(float4*)(h_n + (size_t)(b0 + c) * Hh + noff[nt]) = hn;
            }
        }
        // slot now fully consumed -> reload it with x[t+2]; first use is at the
        // end of step t+2, i.e. ~2 step-bodies of slack for the vmcnt wait.
        int tp = (t + 2 < T) ? t + 2 : T - 1;
#pragma unroll
        for (int nt = 0; nt < 4; nt++)
            xq[nt] = *(const float4*)(xpb + (size_t)tp * Hh + noff[nt]);

        lds_barrier();   // LDS-only: global loads/stores remain in flight
    };

    for (int t = 0; t < T; t += 2) {
        do_step(t,     xq0);
        do_step(t + 1, xq1);
    }
}

// ---------------- GEMM3: tags = sigmoid(hid f16 [32768,256] @ W_out^T + b_out) -> fp32 [32768,512]
__global__ __launch_bounds__(256) void gemm3_tags(const _Float16* __restrict__ A,
                                                  const _Float16* __restrict__ Bw,   // W_out f16 [512,256]
                                                  const float* __restrict__ bias,
                                                  float* __restrict__ C) {
    const int K = 256, N = 512;
    int wave = threadIdx.x >> 6;
    int lane = threadIdx.x & 63;
    int row  = lane & 15;
    int quad = lane >> 4;
    int m0 = blockIdx.x * 64 + wave * 16;
    int n_base = blockIdx.y * 256;

    floatx4 acc[16];
#pragma unroll
    for (int i = 0; i < 16; i++) acc[i] = (floatx4){0.f, 0.f, 0.f, 0.f};

    const _Float16* pa = A + (size_t)(m0 + row) * K + quad * 8;
    for (int k0 = 0; k0 < K; k0 += 32) {
        half8 a = *(const half8*)(pa + k0);
#pragma unroll
        for (int nt = 0; nt < 16; nt++) {
            const _Float16* pb = Bw + (size_t)(n_base + nt * 16 + row) * K + quad * 8 + k0;
            half8 b = *(const half8*)pb;
            acc[nt] = __builtin_amdgcn_mfma_f32_16x16x32_f16(a, b, acc[nt], 0, 0, 0);
        }
    }
#pragma unroll
    for (int nt = 0; nt < 16; nt++) {
        int n = n_base + nt * 16 + row;
        float bn = bias[n];
#pragma unroll
        for (int r = 0; r < 4; r++) {
            int m = m0 + quad * 4 + r;
            float v = acc[nt][r] + bn;
            C[(size_t)m * N + n] = 1.f / (1.f + __expf(-v));
        }
    }
}

extern "C" void kernel_launch(void* const* d_in, const int* in_sizes, int n_in,
                              void* d_out, int out_size, void* d_ws, size_t ws_size,
                              hipStream_t stream) {
    const float* sentence   = (const float*)d_in[0];  // [64,512,512]
    const float* prev_state = (const float*)d_in[1];  // [1,64,256]
    const float* W_ih       = (const float*)d_in[2];  // [256,512]
    const float* b_ih       = (const float*)d_in[3];  // [256]
    const float* W_hh       = (const float*)d_in[4];  // [256,256]
    const float* b_hh       = (const float*)d_in[5];  // [256]
    const float* W_out      = (const float*)d_in[6];  // [512,256]
    const float* b_out      = (const float*)d_in[7];  // [512]

    const size_t WIH_N   = 256u * 512u;
    const size_t WOUT_N  = 512u * 256u;
    const size_t XPROJ_N = 32768u * 256u;
    const size_t HID_N   = 64u * 512u * 256u;

    char* w = (char*)d_ws;
    _Float16* wih_f  = (_Float16*)w;  w += WIH_N * sizeof(_Float16);
    _Float16* wout_f = (_Float16*)w;  w += WOUT_N * sizeof(_Float16);
    float*    xproj  = (float*)w;     w += XPROJ_N * sizeof(float);
    _Float16* hid_f  = (_Float16*)w;  w += HID_N * sizeof(_Float16);

    float* tags = (float*)d_out;
    float* h_n  = (float*)d_out + 16777216;

    conv_f32_f16<<<(int)(WIH_N / 4 / 256),  256, 0, stream>>>(W_ih,  wih_f,  (int)(WIH_N / 4));
    conv_f32_f16<<<(int)(WOUT_N / 4 / 256), 256, 0, stream>>>(W_out, wout_f, (int)(WOUT_N / 4));

    gemm1_xproj<<<512, 256, 0, stream>>>(sentence, wih_f, b_ih, b_hh, xproj);

    rnn_recur<<<4, 256, 0, stream>>>(xproj, prev_state, W_hh, hid_f, h_n);

    gemm3_tags<<<dim3(512, 2), 256, 0, stream>>>(hid_f, wout_f, b_out, tags);
}

// Round 5
// 615.305 us; speedup vs baseline: 2.1986x; 1.1022x over previous
//
#include <hip/hip_runtime.h>
#include <hip/hip_bf16.h>

// Dims: B=64, T=512, V=512, H=256, O=512. M1 = B*T = 32768.
// d_in: sentence, prev_state, W_ih, b_ih, W_hh, b_hh, W_out, b_out
// d_out: tags [B,T,O] fp32 (16777216) then h_n [1,B,H] fp32 (16384)

typedef __attribute__((ext_vector_type(8))) _Float16 half8;
typedef __attribute__((ext_vector_type(4))) _Float16 half4;
typedef __attribute__((ext_vector_type(4))) float   floatx4;

// LDS-only barrier: waits LDS ops, does NOT drain vmcnt — global loads/stores
// stay in flight across it.
__device__ __forceinline__ void lds_barrier() {
    asm volatile("s_waitcnt lgkmcnt(0)\n\ts_barrier" ::: "memory");
}

// ---------------- fp32 -> fp16 convert (vector4) ----------------
__global__ void conv_f32_f16(const float* __restrict__ in, _Float16* __restrict__ out, int n4) {
    int idx = blockIdx.x * blockDim.x + threadIdx.x;
    if (idx >= n4) return;
    float4 v = ((const float4*)in)[idx];
    half4 h = { (_Float16)v.x, (_Float16)v.y, (_Float16)v.z, (_Float16)v.w };
    ((half4*)out)[idx] = h;
}

// ---------------- GEMM1: xp = sentence [32768,512] @ W_ih^T + (b_ih + b_hh) -> fp32 [B,T,H]
__global__ __launch_bounds__(256) void gemm1_xproj(const float* __restrict__ A,      // sentence fp32
                                                   const _Float16* __restrict__ Bw,  // W_ih f16 [256,512]
                                                   const float* __restrict__ b_ih,
                                                   const float* __restrict__ b_hh,
                                                   float* __restrict__ C) {          // [32768,256]
    const int K = 512, N = 256;
    int wave = threadIdx.x >> 6;
    int lane = threadIdx.x & 63;
    int row  = lane & 15;
    int quad = lane >> 4;
    int m0 = blockIdx.x * 64 + wave * 16;

    floatx4 acc[16];
#pragma unroll
    for (int i = 0; i < 16; i++) acc[i] = (floatx4){0.f, 0.f, 0.f, 0.f};

    const float* pa = A + (size_t)(m0 + row) * K + quad * 8;
    for (int k0 = 0; k0 < K; k0 += 32) {
        float4 a0 = *(const float4*)(pa + k0);
        float4 a1 = *(const float4*)(pa + k0 + 4);
        half8 a = { (_Float16)a0.x, (_Float16)a0.y, (_Float16)a0.z, (_Float16)a0.w,
                    (_Float16)a1.x, (_Float16)a1.y, (_Float16)a1.z, (_Float16)a1.w };
#pragma unroll
        for (int nt = 0; nt < 16; nt++) {
            const _Float16* pb = Bw + (size_t)(nt * 16 + row) * K + quad * 8 + k0;
            half8 b = *(const half8*)pb;
            acc[nt] = __builtin_amdgcn_mfma_f32_16x16x32_f16(a, b, acc[nt], 0, 0, 0);
        }
    }
#pragma unroll
    for (int nt = 0; nt < 16; nt++) {
        int n = nt * 16 + row;
        float bn = b_ih[n] + b_hh[n];
#pragma unroll
        for (int r = 0; r < 4; r++) {
            int m = m0 + quad * 4 + r;
            C[(size_t)m * N + n] = acc[nt][r] + bn;
        }
    }
}

// ---------------- Recurrence (MFMA): 4 blocks x 16 batch rows, 512 threads (8 waves, 2/SIMD).
// Round-4 lesson: at 1 wave/SIMD the wave's single issue stream serializes
// MFMA issue (+620cyc) with epilogue VALU (+450) with all latencies -> 1985cyc/step.
// 2 waves/SIMD restores TLP (m114: MFMA+VALU pipes co-schedule across waves).
// Each wave: 2 n-tiles, 16 MFMA/step, 4 independent acc chains (kt-split).
__global__ __launch_bounds__(512, 2) void rnn_recur(const float* __restrict__ xp,    // [B,T,H] fp32 (bias incl.)
                                                    const float* __restrict__ h0,    // [1,B,H] fp32
                                                    const float* __restrict__ W_hh,  // [H,H] fp32
                                                    _Float16* __restrict__ hid,      // f16 [B,T,H] capped
                                                    float* __restrict__ h_n) {       // [B,H] fp32
    const int Hh = 256, T = 512, LD = 264;   // LDS row stride in halves
    int b0   = blockIdx.x * 16;
    int wave = threadIdx.x >> 6;
    int lane = threadIdx.x & 63;
    int c    = lane & 15;       // batch col within tile
    int q    = lane >> 4;

    // W_hh fragments: wf[nt][kt], n = (wave*2+nt)*16 + c, k = kt*32 + q*8
    half8 wf[2][8];
#pragma unroll
    for (int nt = 0; nt < 2; nt++) {
        int n = (wave * 2 + nt) * 16 + c;
        const float* wr = W_hh + (size_t)n * Hh + q * 8;
#pragma unroll
        for (int kt = 0; kt < 8; kt++) {
            float4 x0 = *(const float4*)(wr + kt * 32);
            float4 x1 = *(const float4*)(wr + kt * 32 + 4);
            wf[nt][kt] = (half8){ (_Float16)x0.x, (_Float16)x0.y, (_Float16)x0.z, (_Float16)x0.w,
                                  (_Float16)x1.x, (_Float16)x1.y, (_Float16)x1.z, (_Float16)x1.w };
        }
    }

    __shared__ _Float16 hb[2][16][LD];
    for (int idx = threadIdx.x; idx < 16 * 256; idx += 512) {
        int m = idx >> 8, k = idx & 255;
        hb[0][m][k] = (_Float16)h0[(size_t)(b0 + m) * Hh + k];
    }
    __syncthreads();   // once, before the loop

    const float* xpb = xp + (size_t)(b0 + c) * T * Hh;
    _Float16* hidb = hid + (size_t)(b0 + c) * T * Hh;

    int noff[2];
#pragma unroll
    for (int nt = 0; nt < 2; nt++) noff[nt] = (wave * 2 + nt) * 16 + q * 4;

    // two prefetch slots: slot0 = even steps, slot1 = odd steps
    float4 xq0[2], xq1[2];
#pragma unroll
    for (int nt = 0; nt < 2; nt++) {
        xq0[nt] = *(const float4*)(xpb + (size_t)0 * Hh + noff[nt]);
        xq1[nt] = *(const float4*)(xpb + (size_t)1 * Hh + noff[nt]);
    }

    auto do_step = [&](int t, float4 (&xq)[2]) {
        const _Float16* hr = &hb[t & 1][0][0];
        // 4 independent chains: (nt=0,1) x (k-low, k-high), each 4 MFMAs deep
        floatx4 aA0 = {0.f,0.f,0.f,0.f}, aA1 = {0.f,0.f,0.f,0.f};
        floatx4 aB0 = {0.f,0.f,0.f,0.f}, aB1 = {0.f,0.f,0.f,0.f};
#pragma unroll
        for (int kt = 0; kt < 4; kt++) {
            half8 hfA = *(const half8*)(hr + c * LD + kt * 32 + q * 8);
            half8 hfB = *(const half8*)(hr + c * LD + (kt + 4) * 32 + q * 8);
            aA0 = __builtin_amdgcn_mfma_f32_16x16x32_f16(wf[0][kt],     hfA, aA0, 0, 0, 0);
            aB0 = __builtin_amdgcn_mfma_f32_16x16x32_f16(wf[0][kt + 4], hfB, aB0, 0, 0, 0);
            aA1 = __builtin_amdgcn_mfma_f32_16x16x32_f16(wf[1][kt],     hfA, aA1, 0, 0, 0);
            aB1 = __builtin_amdgcn_mfma_f32_16x16x32_f16(wf[1][kt + 4], hfB, aB1, 0, 0, 0);
        }
        floatx4 acc[2];
        acc[0] = aA0 + aB0;
        acc[1] = aA1 + aB1;

        _Float16* hw = &hb[(t + 1) & 1][0][0];
#pragma unroll
        for (int nt = 0; nt < 2; nt++) {
            float v0 = fmaxf(acc[nt][0] + xq[nt].x, 0.f);
            float v1 = fmaxf(acc[nt][1] + xq[nt].y, 0.f);
            float v2 = fmaxf(acc[nt][2] + xq[nt].z, 0.f);
            float v3 = fmaxf(acc[nt][3] + xq[nt].w, 0.f);
            half4 hv = { (_Float16)v0, (_Float16)v1, (_Float16)v2, (_Float16)v3 };
            *(half4*)(hw + c * LD + noff[nt]) = hv;                       // next step's B source
            half4 hc = { (_Float16)fminf(v0, 1.f), (_Float16)fminf(v1, 1.f),
                         (_Float16)fminf(v2, 1.f), (_Float16)fminf(v3, 1.f) };
            *(half4*)(hidb + (size_t)t * Hh + noff[nt]) = hc;             // capped hidden for GEMM3
            if (t == T - 1) {
                float4 hn = { v0, v1, v2, v3 };
                *(float4*)(h_n + (size_t)(b0 + c) * Hh + noff[nt]) = hn;
            }
        }
        // slot fully consumed -> reload with x[t+2]; first use at end of step t+2
        int tp = (t + 2 < T) ? t + 2 : T - 1;
#pragma unroll
        for (int nt = 0; nt < 2; nt++)
            xq[nt] = *(const float4*)(xpb + (size_t)tp * Hh + noff[nt]);

        lds_barrier();   // LDS-only: global loads/stores remain in flight
    };

    for (int t = 0; t < T; t += 2) {
        do_step(t,     xq0);
        do_step(t + 1, xq1);
    }
}

// ---------------- GEMM3: tags = sigmoid(hid f16 [32768,256] @ W_out^T + b_out) -> fp32 [32768,512]
__global__ __launch_bounds__(256) void gemm3_tags(const _Float16* __restrict__ A,
                                                  const _Float16* __restrict__ Bw,   // W_out f16 [512,256]
                                                  const float* __restrict__ bias,
                                                  float* __restrict__ C) {
    const int K = 256, N = 512;
    int wave = threadIdx.x >> 6;
    int lane = threadIdx.x & 63;
    int row  = lane & 15;
    int quad = lane >> 4;
    int m0 = blockIdx.x * 64 + wave * 16;
    int n_base = blockIdx.y * 256;

    floatx4 acc[16];
#pragma unroll
    for (int i = 0; i < 16; i++) acc[i] = (floatx4){0.f, 0.f, 0.f, 0.f};

    const _Float16* pa = A + (size_t)(m0 + row) * K + quad * 8;
    for (int k0 = 0; k0 < K; k0 += 32) {
        half8 a = *(const half8*)(pa + k0);
#pragma unroll
        for (int nt = 0; nt < 16; nt++) {
            const _Float16* pb = Bw + (size_t)(n_base + nt * 16 + row) * K + quad * 8 + k0;
            half8 b = *(const half8*)pb;
            acc[nt] = __builtin_amdgcn_mfma_f32_16x16x32_f16(a, b, acc[nt], 0, 0, 0);
        }
    }
#pragma unroll
    for (int nt = 0; nt < 16; nt++) {
        int n = n_base + nt * 16 + row;
        float bn = bias[n];
#pragma unroll
        for (int r = 0; r < 4; r++) {
            int m = m0 + quad * 4 + r;
            float v = acc[nt][r] + bn;
            C[(size_t)m * N + n] = 1.f / (1.f + __expf(-v));
        }
    }
}

extern "C" void kernel_launch(void* const* d_in, const int* in_sizes, int n_in,
                              void* d_out, int out_size, void* d_ws, size_t ws_size,
                              hipStream_t stream) {
    const float* sentence   = (const float*)d_in[0];  // [64,512,512]
    const float* prev_state = (const float*)d_in[1];  // [1,64,256]
    const float* W_ih       = (const float*)d_in[2];  // [256,512]
    const float* b_ih       = (const float*)d_in[3];  // [256]
    const float* W_hh       = (const float*)d_in[4];  // [256,256]
    const float* b_hh       = (const float*)d_in[5];  // [256]
    const float* W_out      = (const float*)d_in[6];  // [512,256]
    const float* b_out      = (const float*)d_in[7];  // [512]

    const size_t WIH_N   = 256u * 512u;
    const size_t WOUT_N  = 512u * 256u;
    const size_t XPROJ_N = 32768u * 256u;
    const size_t HID_N   = 64u * 512u * 256u;

    char* w = (char*)d_ws;
    _Float16* wih_f  = (_Float16*)w;  w += WIH_N * sizeof(_Float16);
    _Float16* wout_f = (_Float16*)w;  w += WOUT_N * sizeof(_Float16);
    float*    xproj  = (float*)w;     w += XPROJ_N * sizeof(float);
    _Float16* hid_f  = (_Float16*)w;  w += HID_N * sizeof(_Float16);

    float* tags = (float*)d_out;
    float* h_n  = (float*)d_out + 16777216;

    conv_f32_f16<<<(int)(WIH_N / 4 / 256),  256, 0, stream>>>(W_ih,  wih_f,  (int)(WIH_N / 4));
    conv_f32_f16<<<(int)(WOUT_N / 4 / 256), 256, 0, stream>>>(W_out, wout_f, (int)(WOUT_N / 4));

    gemm1_xproj<<<512, 256, 0, stream>>>(sentence, wih_f, b_ih, b_hh, xproj);

    rnn_recur<<<4, 512, 0, stream>>>(xproj, prev_state, W_hh, hid_f, h_n);

    gemm3_tags<<<dim3(512, 2), 256, 0, stream>>>(hid_f, wout_f, b_out, tags);
}